// Round 9
// baseline (227.632 us; speedup 1.0000x reference)
//
#include <hip/hip_runtime.h>
#include <stdint.h>

typedef __attribute__((ext_vector_type(8))) __bf16 bf16x8;
typedef __attribute__((ext_vector_type(4))) float f32x4;
typedef __attribute__((ext_vector_type(8))) unsigned short ushort8;
typedef __attribute__((ext_vector_type(4))) unsigned short ushort4v;
typedef unsigned short u16;
typedef unsigned int u32;

__device__ __forceinline__ u16 f2bf(float f) {
    __bf16 h = (__bf16)f;
    return __builtin_bit_cast(u16, h);
}

__device__ __forceinline__ f32x4 mfma16(bf16x8 a, bf16x8 b, f32x4 c) {
    return __builtin_amdgcn_mfma_f32_16x16x32_bf16(a, b, c, 0, 0, 0);
}

typedef __attribute__((address_space(1))) const char g_char;
typedef __attribute__((address_space(3))) char l_char;
__device__ __forceinline__ void gload_lds16(const void* g, void* l) {
    __builtin_amdgcn_global_load_lds((g_char*)g, (l_char*)l, 16, 0, 0);
}

// ---------------------------------------------------------------------------
// Weight prep: WT[j][k] = W_sel[k][j%256] as bf16 (j<256:Wq, <512:Wk, <768:Wv)
//              WOT[o][h] = Wo[h][o] as bf16
// ---------------------------------------------------------------------------
__global__ __launch_bounds__(256) void prep_w(
    const float* __restrict__ Wq, const float* __restrict__ Wk,
    const float* __restrict__ Wv, const float* __restrict__ Wo,
    u16* __restrict__ WT, u16* __restrict__ WOT)
{
    int idx = blockIdx.x * 256 + threadIdx.x;  // 0..262143
    if (idx < 196608) {
        int j = idx >> 8, k = idx & 255;
        const float* W = (j < 256) ? Wq : (j < 512) ? Wk : Wv;
        WT[idx] = f2bf(W[k * 256 + (j & 255)]);
    } else {
        int t = idx - 196608;
        int j = t >> 8, k = t & 255;
        WOT[t] = f2bf(Wo[k * 256 + j]);
    }
}

// ---------------------------------------------------------------------------
// QKV projection: C[65536,768] = relu(X[65536,256] @ W + b), bf16 out.
// ---------------------------------------------------------------------------
__global__ __launch_bounds__(256, 2) void qkv_gemm(
    const float* __restrict__ X, const u16* __restrict__ WT,
    const float* __restrict__ bQ, const float* __restrict__ bK,
    const float* __restrict__ bV,
    u16* __restrict__ outQ, u16* __restrict__ outK, u16* __restrict__ outVT)
{
    __shared__ __align__(16) u16 As[128 * 256];  // 64KB, XOR-swizzled rows
    __shared__ __align__(16) u16 Bs[128 * 64];   // 16KB, XOR-swizzled rows
    const int tid = threadIdx.x;
    const int m0 = blockIdx.x * 128;

    #pragma unroll
    for (int i = 0; i < 32; ++i) {
        int flat = (i * 256 + tid) * 4;
        int r = flat >> 8, c = flat & 255;
        const f32x4 f = *reinterpret_cast<const f32x4*>(X + (size_t)(m0 + r) * 256 + c);
        ushort4v h;
        h.x = f2bf(f.x); h.y = f2bf(f.y); h.z = f2bf(f.z); h.w = f2bf(f.w);
        int byte = (r * 512 + c * 2) ^ ((r & 7) << 4);
        *reinterpret_cast<ushort4v*>(reinterpret_cast<char*>(As) + byte) = h;
    }

    const int lane = tid & 63, wid = tid >> 6;
    const int wr = wid >> 1, wc = wid & 1;
    const int lr = lane & 15, lg = lane >> 4;

    for (int cb = 0; cb < 6; ++cb) {
        const int jbase = cb * 128;
        f32x4 acc[4][4];
        #pragma unroll
        for (int a = 0; a < 4; ++a)
            #pragma unroll
            for (int b = 0; b < 4; ++b) acc[a][b] = (f32x4){0.f, 0.f, 0.f, 0.f};

        for (int kk = 0; kk < 256; kk += 64) {
            __syncthreads();
            #pragma unroll
            for (int i = 0; i < 4; ++i) {
                int e = (i * 256 + tid) * 8;
                int r = e >> 6, c = e & 63;
                ushort8 d = *reinterpret_cast<const ushort8*>(WT + (size_t)(jbase + r) * 256 + kk + c);
                int byte = (r * 128 + c * 2) ^ ((r & 7) << 4);
                *reinterpret_cast<ushort8*>(reinterpret_cast<char*>(Bs) + byte) = d;
            }
            __syncthreads();
            #pragma unroll
            for (int ks = 0; ks < 2; ++ks) {
                bf16x8 af[4], bfr[4];
                #pragma unroll
                for (int mt = 0; mt < 4; ++mt) {
                    int r = wr * 64 + mt * 16 + lr;
                    int byte = (r * 512 + (kk + ks * 32 + lg * 8) * 2) ^ ((r & 7) << 4);
                    af[mt] = *reinterpret_cast<const bf16x8*>(reinterpret_cast<const char*>(As) + byte);
                }
                #pragma unroll
                for (int nt = 0; nt < 4; ++nt) {
                    int r = wc * 64 + nt * 16 + lr;
                    int byte = (r * 128 + (ks * 32 + lg * 8) * 2) ^ ((r & 7) << 4);
                    bfr[nt] = *reinterpret_cast<const bf16x8*>(reinterpret_cast<const char*>(Bs) + byte);
                }
                #pragma unroll
                for (int mt = 0; mt < 4; ++mt)
                    #pragma unroll
                    for (int nt = 0; nt < 4; ++nt)
                        acc[mt][nt] = mfma16(af[mt], bfr[nt], acc[mt][nt]);
            }
        }
        const float* bias = (cb < 2) ? bQ : (cb < 4) ? bK : bV;
        float bcol[4];
        #pragma unroll
        for (int nt = 0; nt < 4; ++nt)
            bcol[nt] = bias[(jbase + wc * 64 + nt * 16 + lr) & 255];
        #pragma unroll
        for (int mt = 0; mt < 4; ++mt) {
            #pragma unroll
            for (int nt = 0; nt < 4; ++nt) {
                #pragma unroll
                for (int j = 0; j < 4; ++j) {
                    float v = fmaxf(acc[mt][nt][j] + bcol[nt], 0.f);
                    u16 h = f2bf(v);
                    int row = m0 + wr * 64 + mt * 16 + lg * 4 + j;
                    int col = jbase + wc * 64 + nt * 16 + lr;
                    if (cb < 2) {
                        outQ[(size_t)row * 256 + col] = h;
                    } else if (cb < 4) {
                        outK[(size_t)row * 256 + (col - 256)] = h;
                    } else {
                        int bb = row >> 9, n = row & 511;
                        outVT[(size_t)bb * 131072 + (size_t)(col - 512) * 512 + n] = h;
                    }
                }
            }
        }
    }
}

// ---------------------------------------------------------------------------
// Flash attention r9 = r8 loop (unchanged) + fused output projection.
// After the kt loop: AO (normalized, bf16) -> per-wave LDS (reusing K/V LDS,
// swizzled rows) -> MFMA vs WOT (L2-hot) -> relu+bias -> f32 out directly.
// Deletes the out_gemm kernel (AO 32MB write + 32MB read + launch).
// ---------------------------------------------------------------------------
__global__ __launch_bounds__(512) void attn_kernel(
    const u16* __restrict__ Q, const u16* __restrict__ K,
    const u16* __restrict__ VT, const float* __restrict__ Mask,
    const u16* __restrict__ WOT, const float* __restrict__ bO,
    float* __restrict__ Out)
{
    __shared__ __align__(16) char smem[73728];
    u16* k_lds = reinterpret_cast<u16*>(smem);            // 2 x 16KB
    u16* v_lds = reinterpret_cast<u16*>(smem + 32768);    // 2 x 16KB
    u16* p_lds = reinterpret_cast<u16*>(smem + 65536);    // 8 x 1KB per-wave
    const int tid = threadIdx.x;          // 0..511
    const int b  = blockIdx.x & 127;      // batch; 4 blocks/batch on one XCD
    const int rb = blockIdx.x >> 7;       // 0..3
    const int lane = tid & 63, wid = tid >> 6;
    const int lr = lane & 15, lg = lane >> 4;
    const int n0 = rb * 128 + wid * 16;
    const u16* qbat = Q  + (size_t)b * 131072;
    const u16* kbat = K  + (size_t)b * 131072;
    const u16* vbat = VT + (size_t)b * 131072;
    const float* mrow = Mask + ((size_t)b * 512 + n0 + lg * 4) * 512;

    auto stage = [&](int buf, int kt) {
        #pragma unroll
        for (int i = 0; i < 2; ++i) {
            int p = (i * 512 + tid) * 16;
            int krow = p >> 9, kcol2 = p & 511;
            int scol2 = kcol2 ^ ((krow & 7) << 4);
            const char* gk = reinterpret_cast<const char*>(kbat + (size_t)(kt * 32 + krow) * 256) + scol2;
            char* lk = reinterpret_cast<char*>(k_lds) + buf * 16384 + i * 8192 + wid * 1024;
            gload_lds16(gk, lk);
            int vrow = p >> 6, vcol2 = p & 63;
            const char* gv = reinterpret_cast<const char*>(vbat + (size_t)vrow * 512 + kt * 32) + vcol2;
            char* lv = reinterpret_cast<char*>(v_lds) + buf * 16384 + i * 8192 + wid * 1024;
            gload_lds16(gv, lv);
        }
    };

    // persistent Q fragments: rows n0+lr, all 256 K-dim (8 chunks of 32)
    bf16x8 qf[8];
    #pragma unroll
    for (int ks = 0; ks < 8; ++ks)
        qf[ks] = *reinterpret_cast<const bf16x8*>(
            qbat + (size_t)(n0 + lr) * 256 + ks * 32 + lg * 8);

    stage(0, 0);
    float mf[2][4];
    #pragma unroll
    for (int ct = 0; ct < 2; ++ct)
        #pragma unroll
        for (int j = 0; j < 4; ++j)
            mf[ct][j] = __builtin_nontemporal_load(mrow + (size_t)j * 512 + ct * 16 + lr);

    f32x4 acc[16];
    #pragma unroll
    for (int i = 0; i < 16; ++i) acc[i] = (f32x4){0.f, 0.f, 0.f, 0.f};
    float mreg[4], lreg[4];
    #pragma unroll
    for (int j = 0; j < 4; ++j) { mreg[j] = -__builtin_inff(); lreg[j] = 0.f; }

    __syncthreads();

    for (int kt = 0; kt < 16; ++kt) {
        const int cur = kt & 1;
        if (kt < 15) stage(cur ^ 1, kt + 1);

        u32 mb = 0;
        #pragma unroll
        for (int ct = 0; ct < 2; ++ct)
            #pragma unroll
            for (int j = 0; j < 4; ++j)
                mb |= (mf[ct][j] > 0.5f ? 1u : 0u) << (ct * 4 + j);
        if (kt < 15) {
            #pragma unroll
            for (int ct = 0; ct < 2; ++ct)
                #pragma unroll
                for (int j = 0; j < 4; ++j)
                    mf[ct][j] = __builtin_nontemporal_load(
                        mrow + (size_t)j * 512 + (kt + 1) * 32 + ct * 16 + lr);
        }

        // ---- QK^T: 16 rows x 32 keys per wave, Q from registers ----
        f32x4 s[2];
        s[0] = (f32x4){0.f, 0.f, 0.f, 0.f};
        s[1] = (f32x4){0.f, 0.f, 0.f, 0.f};
        const char* kbase = reinterpret_cast<const char*>(k_lds) + cur * 16384;
        __builtin_amdgcn_s_setprio(1);
        #pragma unroll
        for (int ks = 0; ks < 8; ++ks) {
            #pragma unroll
            for (int ct = 0; ct < 2; ++ct) {
                int krow = ct * 16 + lr;
                int byte = (krow * 512 + (ks * 32 + lg * 8) * 2) ^ ((krow & 7) << 4);
                bf16x8 kf = *reinterpret_cast<const bf16x8*>(kbase + byte);
                s[ct] = mfma16(qf[ks], kf, s[ct]);
            }
        }
        __builtin_amdgcn_s_setprio(0);

        // ---- mask select + online softmax (defer-rescale) ----
        float p[2][4];
        #pragma unroll
        for (int ct = 0; ct < 2; ++ct)
            #pragma unroll
            for (int j = 0; j < 4; ++j)
                p[ct][j] = ((mb >> (ct * 4 + j)) & 1u) ? s[ct][j] : -9.0e15f;

        float r0j[4];
        bool need = false;
        #pragma unroll
        for (int j = 0; j < 4; ++j) {
            float r0 = fmaxf(p[0][j], p[1][j]);
            r0 = fmaxf(r0, __shfl_xor(r0, 1));
            r0 = fmaxf(r0, __shfl_xor(r0, 2));
            r0 = fmaxf(r0, __shfl_xor(r0, 4));
            r0 = fmaxf(r0, __shfl_xor(r0, 8));
            r0j[j] = r0;
            need = need || (r0 > mreg[j]);
        }
        if (__any(need)) {
            #pragma unroll
            for (int j = 0; j < 4; ++j) {
                float mnew = fmaxf(mreg[j], r0j[j]);
                float sc = __expf(mreg[j] - mnew);
                mreg[j] = mnew;
                lreg[j] *= sc;
                #pragma unroll
                for (int ht = 0; ht < 16; ++ht) acc[ht][j] *= sc;
            }
        }
        #pragma unroll
        for (int j = 0; j < 4; ++j) {
            float ps = 0.f;
            #pragma unroll
            for (int ct = 0; ct < 2; ++ct) {
                float e = __expf(p[ct][j] - mreg[j]);
                p[ct][j] = e;
                ps += e;
            }
            lreg[j] += ps;
        }

        // ---- P (D-layout) -> per-wave LDS [16 rows][32 keys], 64B rows ----
        #pragma unroll
        for (int ct = 0; ct < 2; ++ct)
            #pragma unroll
            for (int j = 0; j < 4; ++j) {
                int byte = (lg * 4 + j) * 64 + (ct * 16 + lr) * 2;
                *reinterpret_cast<u16*>(reinterpret_cast<char*>(p_lds) + wid * 1024 + byte) = f2bf(p[ct][j]);
            }

        // ---- PV: acc[16 rows][256 h] += P[16][32] @ V[32][256] ----
        bf16x8 pf = *reinterpret_cast<const bf16x8*>(
            reinterpret_cast<const char*>(p_lds) + wid * 1024 + lr * 64 + lg * 16);
        const char* vbase = reinterpret_cast<const char*>(v_lds) + cur * 16384;
        __builtin_amdgcn_s_setprio(1);
        #pragma unroll
        for (int ht = 0; ht < 16; ++ht) {
            bf16x8 vf = *reinterpret_cast<const bf16x8*>(vbase + (ht * 16 + lr) * 64 + lg * 16);
            acc[ht] = mfma16(pf, vf, acc[ht]);
        }
        __builtin_amdgcn_s_setprio(0);

        __syncthreads();  // next tile staged (vmcnt drained); LDS reads done
    }

    // ------------------------------------------------------------------
    // Fused output projection epilogue.
    // 1) normalize AO and write bf16 into per-wave LDS tile [16][256],
    //    XOR-swizzled rows (same scheme as GEMM A-tiles).
    // All waves are past the final barrier, so K/V LDS is dead -> reuse.
    // ------------------------------------------------------------------
    char* ao = smem + wid * 8192;  // 16 rows x 512B
    #pragma unroll
    for (int j = 0; j < 4; ++j) {
        float lt = lreg[j];
        lt += __shfl_xor(lt, 1);
        lt += __shfl_xor(lt, 2);
        lt += __shfl_xor(lt, 4);
        lt += __shfl_xor(lt, 8);
        float inv = 1.0f / lt;
        int row = lg * 4 + j;
        #pragma unroll
        for (int ht = 0; ht < 16; ++ht) {
            int byte = (row * 512 + (ht * 16 + lr) * 2) ^ ((row & 7) << 4);
            *reinterpret_cast<u16*>(ao + byte) = f2bf(acc[ht][j] * inv);
        }
    }

    // 2) per-wave GEMM: out[16 rows][256] = relu(AO[16][256] @ WOT^T + bO)
    //    A-frags from own LDS tile; B-frags (WOT[oc][k]) from L2-hot global.
    f32x4 oacc[16];
    #pragma unroll
    for (int i = 0; i < 16; ++i) oacc[i] = (f32x4){0.f, 0.f, 0.f, 0.f};
    #pragma unroll
    for (int ks = 0; ks < 8; ++ks) {
        int abyte = (lr * 512 + (ks * 32 + lg * 8) * 2) ^ ((lr & 7) << 4);
        bf16x8 af = *reinterpret_cast<const bf16x8*>(ao + abyte);
        __builtin_amdgcn_s_setprio(1);
        #pragma unroll
        for (int ct = 0; ct < 16; ++ct) {
            bf16x8 bf = *reinterpret_cast<const bf16x8*>(
                WOT + (size_t)(ct * 16 + lr) * 256 + ks * 32 + lg * 8);
            oacc[ct] = mfma16(af, bf, oacc[ct]);
        }
        __builtin_amdgcn_s_setprio(0);
    }

    // 3) bias + relu + f32 store
    float* orow = Out + ((size_t)b * 512 + n0 + lg * 4) * 256;
    #pragma unroll
    for (int ct = 0; ct < 16; ++ct) {
        float bc = bO[ct * 16 + lr];
        #pragma unroll
        for (int j = 0; j < 4; ++j) {
            float v = fmaxf(oacc[ct][j] + bc, 0.f);
            orow[(size_t)j * 256 + ct * 16 + lr] = v;
        }
    }
}

// ---------------------------------------------------------------------------
extern "C" void kernel_launch(void* const* d_in, const int* in_sizes, int n_in,
                              void* d_out, int out_size, void* d_ws, size_t ws_size,
                              hipStream_t stream) {
    const float* x    = (const float*)d_in[0];
    const float* mask = (const float*)d_in[1];
    const float* Wv   = (const float*)d_in[2];
    const float* bv   = (const float*)d_in[3];
    const float* Wk   = (const float*)d_in[4];
    const float* bk   = (const float*)d_in[5];
    const float* Wq   = (const float*)d_in[6];
    const float* bq   = (const float*)d_in[7];
    const float* Wo   = (const float*)d_in[8];
    const float* bo   = (const float*)d_in[9];
    float* out = (float*)d_out;

    char* ws = (char*)d_ws;
    u16* WT  = (u16*)(ws);                          // 768*256 bf16 = 384KB
    u16* WOT = (u16*)(ws + 393216);                 // 256*256 bf16 = 128KB
    u16* Qb  = (u16*)(ws + 524288);                 // 33.55MB
    u16* Kb  = (u16*)(ws + 524288 + 33554432);      // 33.55MB
    u16* VTb = (u16*)(ws + 524288 + 2 * 33554432);  // 33.55MB, [b][h][n]

    prep_w<<<1024, 256, 0, stream>>>(Wq, Wk, Wv, Wo, WT, WOT);
    qkv_gemm<<<512, 256, 0, stream>>>(x, WT, bq, bk, bv, Qb, Kb, VTb);
    attn_kernel<<<512, 512, 0, stream>>>(Qb, Kb, VTb, mask, WOT, bo, out);
}

// Round 10
// 204.443 us; speedup vs baseline: 1.1134x; 1.1134x over previous
//
#include <hip/hip_runtime.h>
#include <stdint.h>

typedef __attribute__((ext_vector_type(8))) __bf16 bf16x8;
typedef __attribute__((ext_vector_type(4))) float f32x4;
typedef __attribute__((ext_vector_type(8))) unsigned short ushort8;
typedef __attribute__((ext_vector_type(4))) unsigned short ushort4v;
typedef unsigned short u16;
typedef unsigned int u32;

__device__ __forceinline__ u16 f2bf(float f) {
    __bf16 h = (__bf16)f;
    return __builtin_bit_cast(u16, h);
}

__device__ __forceinline__ f32x4 mfma16(bf16x8 a, bf16x8 b, f32x4 c) {
    return __builtin_amdgcn_mfma_f32_16x16x32_bf16(a, b, c, 0, 0, 0);
}

typedef __attribute__((address_space(1))) const char g_char;
typedef __attribute__((address_space(3))) char l_char;
__device__ __forceinline__ void gload_lds16(const void* g, void* l) {
    __builtin_amdgcn_global_load_lds((g_char*)g, (l_char*)l, 16, 0, 0);
}

// ---------------------------------------------------------------------------
// Weight prep: WT[j][k] = W_sel[k][j%256] as bf16 (j<256:Wq, <512:Wk, <768:Wv)
//              WOT[o][h] = Wo[h][o] as bf16
// ---------------------------------------------------------------------------
__global__ __launch_bounds__(256) void prep_w(
    const float* __restrict__ Wq, const float* __restrict__ Wk,
    const float* __restrict__ Wv, const float* __restrict__ Wo,
    u16* __restrict__ WT, u16* __restrict__ WOT)
{
    int idx = blockIdx.x * 256 + threadIdx.x;  // 0..262143
    if (idx < 196608) {
        int j = idx >> 8, k = idx & 255;
        const float* W = (j < 256) ? Wq : (j < 512) ? Wk : Wv;
        WT[idx] = f2bf(W[k * 256 + (j & 255)]);
    } else {
        int t = idx - 196608;
        int j = t >> 8, k = t & 255;
        WOT[t] = f2bf(Wo[k * 256 + j]);
    }
}

// ---------------------------------------------------------------------------
// QKV projection: C[65536,768] = relu(X[65536,256] @ W + b), bf16 out.
// ---------------------------------------------------------------------------
__global__ __launch_bounds__(256, 2) void qkv_gemm(
    const float* __restrict__ X, const u16* __restrict__ WT,
    const float* __restrict__ bQ, const float* __restrict__ bK,
    const float* __restrict__ bV,
    u16* __restrict__ outQ, u16* __restrict__ outK, u16* __restrict__ outVT)
{
    __shared__ __align__(16) u16 As[128 * 256];  // 64KB, XOR-swizzled rows
    __shared__ __align__(16) u16 Bs[128 * 64];   // 16KB, XOR-swizzled rows
    const int tid = threadIdx.x;
    const int m0 = blockIdx.x * 128;

    #pragma unroll
    for (int i = 0; i < 32; ++i) {
        int flat = (i * 256 + tid) * 4;
        int r = flat >> 8, c = flat & 255;
        const f32x4 f = *reinterpret_cast<const f32x4*>(X + (size_t)(m0 + r) * 256 + c);
        ushort4v h;
        h.x = f2bf(f.x); h.y = f2bf(f.y); h.z = f2bf(f.z); h.w = f2bf(f.w);
        int byte = (r * 512 + c * 2) ^ ((r & 7) << 4);
        *reinterpret_cast<ushort4v*>(reinterpret_cast<char*>(As) + byte) = h;
    }

    const int lane = tid & 63, wid = tid >> 6;
    const int wr = wid >> 1, wc = wid & 1;
    const int lr = lane & 15, lg = lane >> 4;

    for (int cb = 0; cb < 6; ++cb) {
        const int jbase = cb * 128;
        f32x4 acc[4][4];
        #pragma unroll
        for (int a = 0; a < 4; ++a)
            #pragma unroll
            for (int b = 0; b < 4; ++b) acc[a][b] = (f32x4){0.f, 0.f, 0.f, 0.f};

        for (int kk = 0; kk < 256; kk += 64) {
            __syncthreads();
            #pragma unroll
            for (int i = 0; i < 4; ++i) {
                int e = (i * 256 + tid) * 8;
                int r = e >> 6, c = e & 63;
                ushort8 d = *reinterpret_cast<const ushort8*>(WT + (size_t)(jbase + r) * 256 + kk + c);
                int byte = (r * 128 + c * 2) ^ ((r & 7) << 4);
                *reinterpret_cast<ushort8*>(reinterpret_cast<char*>(Bs) + byte) = d;
            }
            __syncthreads();
            #pragma unroll
            for (int ks = 0; ks < 2; ++ks) {
                bf16x8 af[4], bfr[4];
                #pragma unroll
                for (int mt = 0; mt < 4; ++mt) {
                    int r = wr * 64 + mt * 16 + lr;
                    int byte = (r * 512 + (kk + ks * 32 + lg * 8) * 2) ^ ((r & 7) << 4);
                    af[mt] = *reinterpret_cast<const bf16x8*>(reinterpret_cast<const char*>(As) + byte);
                }
                #pragma unroll
                for (int nt = 0; nt < 4; ++nt) {
                    int r = wc * 64 + nt * 16 + lr;
                    int byte = (r * 128 + (ks * 32 + lg * 8) * 2) ^ ((r & 7) << 4);
                    bfr[nt] = *reinterpret_cast<const bf16x8*>(reinterpret_cast<const char*>(Bs) + byte);
                }
                #pragma unroll
                for (int mt = 0; mt < 4; ++mt)
                    #pragma unroll
                    for (int nt = 0; nt < 4; ++nt)
                        acc[mt][nt] = mfma16(af[mt], bfr[nt], acc[mt][nt]);
            }
        }
        const float* bias = (cb < 2) ? bQ : (cb < 4) ? bK : bV;
        float bcol[4];
        #pragma unroll
        for (int nt = 0; nt < 4; ++nt)
            bcol[nt] = bias[(jbase + wc * 64 + nt * 16 + lr) & 255];
        #pragma unroll
        for (int mt = 0; mt < 4; ++mt) {
            #pragma unroll
            for (int nt = 0; nt < 4; ++nt) {
                #pragma unroll
                for (int j = 0; j < 4; ++j) {
                    float v = fmaxf(acc[mt][nt][j] + bcol[nt], 0.f);
                    u16 h = f2bf(v);
                    int row = m0 + wr * 64 + mt * 16 + lg * 4 + j;
                    int col = jbase + wc * 64 + nt * 16 + lr;
                    if (cb < 2) {
                        outQ[(size_t)row * 256 + col] = h;
                    } else if (cb < 4) {
                        outK[(size_t)row * 256 + (col - 256)] = h;
                    } else {
                        int bb = row >> 9, n = row & 511;
                        outVT[(size_t)bb * 131072 + (size_t)(col - 512) * 512 + n] = h;
                    }
                }
            }
        }
    }
}

// ---------------------------------------------------------------------------
// Flash attention r10 = r8 + counted-vmcnt pipeline (T4).
// Replaces per-iteration __syncthreads (which drains vmcnt(0) — the convoy)
// with raw s_barrier + exact counted s_waitcnt:
//   at top of kt, in flight: S(kt)[4 stage loads, oldest] +
//   masks(kt-1)[8] + S(kt+1)[4 just issued]  ->  vmcnt(12) guarantees S(kt)
//   landed while 12 newer ops stay in flight across the barrier.
// Read-before-overwrite safety: LDS reads are register-consumed (compiler
// lgkmcnt) before the end barrier; stage(kt+1) only issues after it.
// ---------------------------------------------------------------------------
__global__ __launch_bounds__(512) void attn_kernel(
    const u16* __restrict__ Q, const u16* __restrict__ K,
    const u16* __restrict__ VT, const float* __restrict__ Mask,
    u16* __restrict__ Out)
{
    __shared__ __align__(16) u16 k_lds[2][32 * 256];  // 2 x 16KB, XOR-swizzled
    __shared__ __align__(16) u16 v_lds[2][256 * 32];  // 2 x 16KB, linear [h][key]
    __shared__ __align__(16) u16 p_lds[8][16 * 32];   // 8KB, per-wave P
    const int tid = threadIdx.x;          // 0..511
    const int b  = blockIdx.x & 127;      // batch; 4 blocks/batch on one XCD
    const int rb = blockIdx.x >> 7;       // 0..3
    const int lane = tid & 63, wid = tid >> 6;
    const int lr = lane & 15, lg = lane >> 4;
    const int n0 = rb * 128 + wid * 16;
    const u16* qbat = Q  + (size_t)b * 131072;
    const u16* kbat = K  + (size_t)b * 131072;
    const u16* vbat = VT + (size_t)b * 131072;
    const float* mrow = Mask + ((size_t)b * 512 + n0 + lg * 4) * 512;

    auto stage = [&](int buf, int kt) {
        #pragma unroll
        for (int i = 0; i < 2; ++i) {
            int p = (i * 512 + tid) * 16;
            int krow = p >> 9, kcol2 = p & 511;
            int scol2 = kcol2 ^ ((krow & 7) << 4);
            const char* gk = reinterpret_cast<const char*>(kbat + (size_t)(kt * 32 + krow) * 256) + scol2;
            char* lk = reinterpret_cast<char*>(k_lds[buf]) + i * 8192 + wid * 1024;
            gload_lds16(gk, lk);
            int vrow = p >> 6, vcol2 = p & 63;
            const char* gv = reinterpret_cast<const char*>(vbat + (size_t)vrow * 512 + kt * 32) + vcol2;
            char* lv = reinterpret_cast<char*>(v_lds[buf]) + i * 8192 + wid * 1024;
            gload_lds16(gv, lv);
        }
    };

    // persistent Q fragments: rows n0+lr, all 256 K-dim (8 chunks of 32)
    bf16x8 qf[8];
    #pragma unroll
    for (int ks = 0; ks < 8; ++ks)
        qf[ks] = *reinterpret_cast<const bf16x8*>(
            qbat + (size_t)(n0 + lr) * 256 + ks * 32 + lg * 8);

    stage(0, 0);
    float mf[2][4];
    #pragma unroll
    for (int ct = 0; ct < 2; ++ct)
        #pragma unroll
        for (int j = 0; j < 4; ++j)
            mf[ct][j] = __builtin_nontemporal_load(mrow + (size_t)j * 512 + ct * 16 + lr);

    f32x4 acc[16];
    #pragma unroll
    for (int i = 0; i < 16; ++i) acc[i] = (f32x4){0.f, 0.f, 0.f, 0.f};
    float mreg[4], lreg[4];
    #pragma unroll
    for (int j = 0; j < 4; ++j) { mreg[j] = -__builtin_inff(); lreg[j] = 0.f; }

    for (int kt = 0; kt < 16; ++kt) {
        const int cur = kt & 1;
        // issue next tile's staging FIRST (oldest-first vmcnt discipline)
        if (kt < 15) stage(cur ^ 1, kt + 1);

        // counted wait: S(kt) done; masks(kt-1)[8] + S(kt+1)[4] keep flying
        if (kt < 15) asm volatile("s_waitcnt vmcnt(12)" ::: "memory");
        else         asm volatile("s_waitcnt vmcnt(8)"  ::: "memory");
        __builtin_amdgcn_s_barrier();

        // pack current mask bits (compiler waits its own mask loads here),
        // then reuse regs to prefetch next tile's mask
        u32 mb = 0;
        #pragma unroll
        for (int ct = 0; ct < 2; ++ct)
            #pragma unroll
            for (int j = 0; j < 4; ++j)
                mb |= (mf[ct][j] > 0.5f ? 1u : 0u) << (ct * 4 + j);
        if (kt < 15) {
            #pragma unroll
            for (int ct = 0; ct < 2; ++ct)
                #pragma unroll
                for (int j = 0; j < 4; ++j)
                    mf[ct][j] = __builtin_nontemporal_load(
                        mrow + (size_t)j * 512 + (kt + 1) * 32 + ct * 16 + lr);
        }

        // ---- QK^T: 16 rows x 32 keys per wave, Q from registers ----
        f32x4 s[2];
        s[0] = (f32x4){0.f, 0.f, 0.f, 0.f};
        s[1] = (f32x4){0.f, 0.f, 0.f, 0.f};
        const char* kbase = reinterpret_cast<const char*>(k_lds[cur]);
        __builtin_amdgcn_s_setprio(1);
        #pragma unroll
        for (int ks = 0; ks < 8; ++ks) {
            #pragma unroll
            for (int ct = 0; ct < 2; ++ct) {
                int krow = ct * 16 + lr;
                int byte = (krow * 512 + (ks * 32 + lg * 8) * 2) ^ ((krow & 7) << 4);
                bf16x8 kf = *reinterpret_cast<const bf16x8*>(kbase + byte);
                s[ct] = mfma16(qf[ks], kf, s[ct]);
            }
        }
        __builtin_amdgcn_s_setprio(0);

        // ---- mask select + online softmax (defer-rescale) ----
        float p[2][4];
        #pragma unroll
        for (int ct = 0; ct < 2; ++ct)
            #pragma unroll
            for (int j = 0; j < 4; ++j)
                p[ct][j] = ((mb >> (ct * 4 + j)) & 1u) ? s[ct][j] : -9.0e15f;

        float r0j[4];
        bool need = false;
        #pragma unroll
        for (int j = 0; j < 4; ++j) {
            float r0 = fmaxf(p[0][j], p[1][j]);
            r0 = fmaxf(r0, __shfl_xor(r0, 1));
            r0 = fmaxf(r0, __shfl_xor(r0, 2));
            r0 = fmaxf(r0, __shfl_xor(r0, 4));
            r0 = fmaxf(r0, __shfl_xor(r0, 8));
            r0j[j] = r0;
            need = need || (r0 > mreg[j]);
        }
        if (__any(need)) {
            #pragma unroll
            for (int j = 0; j < 4; ++j) {
                float mnew = fmaxf(mreg[j], r0j[j]);
                float sc = __expf(mreg[j] - mnew);
                mreg[j] = mnew;
                lreg[j] *= sc;
                #pragma unroll
                for (int ht = 0; ht < 16; ++ht) acc[ht][j] *= sc;
            }
        }
        #pragma unroll
        for (int j = 0; j < 4; ++j) {
            float ps = 0.f;
            #pragma unroll
            for (int ct = 0; ct < 2; ++ct) {
                float e = __expf(p[ct][j] - mreg[j]);
                p[ct][j] = e;
                ps += e;
            }
            lreg[j] += ps;
        }

        // ---- P (D-layout) -> per-wave LDS [16 rows][32 keys], 64B rows ----
        #pragma unroll
        for (int ct = 0; ct < 2; ++ct)
            #pragma unroll
            for (int j = 0; j < 4; ++j) {
                int byte = (lg * 4 + j) * 64 + (ct * 16 + lr) * 2;
                *reinterpret_cast<u16*>(reinterpret_cast<char*>(p_lds[wid]) + byte) = f2bf(p[ct][j]);
            }

        // ---- PV: acc[16 rows][256 h] += P[16][32] @ V[32][256] ----
        bf16x8 pf = *reinterpret_cast<const bf16x8*>(
            reinterpret_cast<const char*>(p_lds[wid]) + lr * 64 + lg * 16);
        const char* vbase = reinterpret_cast<const char*>(v_lds[cur]);
        __builtin_amdgcn_s_setprio(1);
        #pragma unroll
        for (int ht = 0; ht < 16; ++ht) {
            bf16x8 vf = *reinterpret_cast<const bf16x8*>(vbase + (ht * 16 + lr) * 64 + lg * 16);
            acc[ht] = mfma16(pf, vf, acc[ht]);
        }
        __builtin_amdgcn_s_setprio(0);

        // end barrier: all waves done reading buf `cur` (LDS reads already
        // register-consumed -> retired); no vmcnt drain here.
        __builtin_amdgcn_s_barrier();
    }

    // finalize: normalize and store bf16
    #pragma unroll
    for (int j = 0; j < 4; ++j) {
        float lt = lreg[j];
        lt += __shfl_xor(lt, 1);
        lt += __shfl_xor(lt, 2);
        lt += __shfl_xor(lt, 4);
        lt += __shfl_xor(lt, 8);
        float inv = 1.0f / lt;
        int qn = n0 + lg * 4 + j;
        u16* orow = Out + ((size_t)b * 512 + qn) * 256;
        #pragma unroll
        for (int ht = 0; ht < 16; ++ht)
            orow[ht * 16 + lr] = f2bf(acc[ht][j] * inv);
    }
}

// ---------------------------------------------------------------------------
// Output projection: Out[65536,256] = relu(A[65536,256](bf16) @ Wo + bo), f32.
// ---------------------------------------------------------------------------
__global__ __launch_bounds__(256, 2) void out_gemm(
    const u16* __restrict__ A, const u16* __restrict__ WOT,
    const float* __restrict__ bO, float* __restrict__ Out)
{
    __shared__ __align__(16) u16 As[128 * 256];
    __shared__ __align__(16) u16 Bs[128 * 64];
    const int tid = threadIdx.x;
    const int m0 = blockIdx.x * 128;

    #pragma unroll
    for (int i = 0; i < 16; ++i) {
        int e = (i * 256 + tid) * 8;
        int r = e >> 8, c = e & 255;
        ushort8 d = *reinterpret_cast<const ushort8*>(A + (size_t)(m0 + r) * 256 + c);
        int byte = (r * 512 + c * 2) ^ ((r & 7) << 4);
        *reinterpret_cast<ushort8*>(reinterpret_cast<char*>(As) + byte) = d;
    }

    const int lane = tid & 63, wid = tid >> 6;
    const int wr = wid >> 1, wc = wid & 1;
    const int lr = lane & 15, lg = lane >> 4;

    for (int cb = 0; cb < 2; ++cb) {
        const int jbase = cb * 128;
        f32x4 acc[4][4];
        #pragma unroll
        for (int a = 0; a < 4; ++a)
            #pragma unroll
            for (int b = 0; b < 4; ++b) acc[a][b] = (f32x4){0.f, 0.f, 0.f, 0.f};

        for (int kk = 0; kk < 256; kk += 64) {
            __syncthreads();
            #pragma unroll
            for (int i = 0; i < 4; ++i) {
                int e = (i * 256 + tid) * 8;
                int r = e >> 6, c = e & 63;
                ushort8 d = *reinterpret_cast<const ushort8*>(WOT + (size_t)(jbase + r) * 256 + kk + c);
                int byte = (r * 128 + c * 2) ^ ((r & 7) << 4);
                *reinterpret_cast<ushort8*>(reinterpret_cast<char*>(Bs) + byte) = d;
            }
            __syncthreads();
            #pragma unroll
            for (int ks = 0; ks < 2; ++ks) {
                bf16x8 af[4], bfr[4];
                #pragma unroll
                for (int mt = 0; mt < 4; ++mt) {
                    int r = wr * 64 + mt * 16 + lr;
                    int byte = (r * 512 + (kk + ks * 32 + lg * 8) * 2) ^ ((r & 7) << 4);
                    af[mt] = *reinterpret_cast<const bf16x8*>(reinterpret_cast<const char*>(As) + byte);
                }
                #pragma unroll
                for (int nt = 0; nt < 4; ++nt) {
                    int r = wc * 64 + nt * 16 + lr;
                    int byte = (r * 128 + (ks * 32 + lg * 8) * 2) ^ ((r & 7) << 4);
                    bfr[nt] = *reinterpret_cast<const bf16x8*>(reinterpret_cast<const char*>(Bs) + byte);
                }
                #pragma unroll
                for (int mt = 0; mt < 4; ++mt)
                    #pragma unroll
                    for (int nt = 0; nt < 4; ++nt)
                        acc[mt][nt] = mfma16(af[mt], bfr[nt], acc[mt][nt]);
            }
        }
        float bcol[4];
        #pragma unroll
        for (int nt = 0; nt < 4; ++nt)
            bcol[nt] = bO[jbase + wc * 64 + nt * 16 + lr];
        #pragma unroll
        for (int mt = 0; mt < 4; ++mt) {
            #pragma unroll
            for (int nt = 0; nt < 4; ++nt) {
                #pragma unroll
                for (int j = 0; j < 4; ++j) {
                    float v = fmaxf(acc[mt][nt][j] + bcol[nt], 0.f);
                    int row = m0 + wr * 64 + mt * 16 + lg * 4 + j;
                    int col = jbase + wc * 64 + nt * 16 + lr;
                    Out[(size_t)row * 256 + col] = v;
                }
            }
        }
    }
}

// ---------------------------------------------------------------------------
extern "C" void kernel_launch(void* const* d_in, const int* in_sizes, int n_in,
                              void* d_out, int out_size, void* d_ws, size_t ws_size,
                              hipStream_t stream) {
    const float* x    = (const float*)d_in[0];
    const float* mask = (const float*)d_in[1];
    const float* Wv   = (const float*)d_in[2];
    const float* bv   = (const float*)d_in[3];
    const float* Wk   = (const float*)d_in[4];
    const float* bk   = (const float*)d_in[5];
    const float* Wq   = (const float*)d_in[6];
    const float* bq   = (const float*)d_in[7];
    const float* Wo   = (const float*)d_in[8];
    const float* bo   = (const float*)d_in[9];
    float* out = (float*)d_out;

    char* ws = (char*)d_ws;
    u16* WT  = (u16*)(ws);                          // 768*256 bf16 = 384KB
    u16* WOT = (u16*)(ws + 393216);                 // 256*256 bf16 = 128KB
    u16* Qb  = (u16*)(ws + 524288);                 // 33.55MB (also attn out)
    u16* Kb  = (u16*)(ws + 524288 + 33554432);      // 33.55MB
    u16* VTb = (u16*)(ws + 524288 + 2 * 33554432);  // 33.55MB, [b][h][n]

    prep_w<<<1024, 256, 0, stream>>>(Wq, Wk, Wv, Wo, WT, WOT);
    qkv_gemm<<<512, 256, 0, stream>>>(x, WT, bq, bk, bv, Qb, Kb, VTb);
    attn_kernel<<<512, 512, 0, stream>>>(Qb, Kb, VTb, mask, Qb);
    out_gemm<<<512, 256, 0, stream>>>(Qb, WOT, bo, out);
}

// Round 11
// 187.475 us; speedup vs baseline: 1.2142x; 1.0905x over previous
//
#include <hip/hip_runtime.h>
#include <stdint.h>

typedef __attribute__((ext_vector_type(8))) __bf16 bf16x8;
typedef __attribute__((ext_vector_type(4))) float f32x4;
typedef __attribute__((ext_vector_type(8))) unsigned short ushort8;
typedef __attribute__((ext_vector_type(4))) unsigned short ushort4v;
typedef unsigned short u16;
typedef unsigned int u32;

__device__ __forceinline__ u16 f2bf(float f) {
    __bf16 h = (__bf16)f;
    return __builtin_bit_cast(u16, h);
}

__device__ __forceinline__ f32x4 mfma16(bf16x8 a, bf16x8 b, f32x4 c) {
    return __builtin_amdgcn_mfma_f32_16x16x32_bf16(a, b, c, 0, 0, 0);
}

typedef __attribute__((address_space(1))) const char g_char;
typedef __attribute__((address_space(3))) char l_char;
__device__ __forceinline__ void gload_lds16(const void* g, void* l) {
    __builtin_amdgcn_global_load_lds((g_char*)g, (l_char*)l, 16, 0, 0);
}

// ---------------------------------------------------------------------------
// Weight prep: WT[j][k] = W_sel[k][j%256] as bf16 (j<256:Wq, <512:Wk, <768:Wv)
//              WOT[o][h] = Wo[h][o] as bf16
// ---------------------------------------------------------------------------
__global__ __launch_bounds__(256) void prep_w(
    const float* __restrict__ Wq, const float* __restrict__ Wk,
    const float* __restrict__ Wv, const float* __restrict__ Wo,
    u16* __restrict__ WT, u16* __restrict__ WOT)
{
    int idx = blockIdx.x * 256 + threadIdx.x;  // 0..262143
    if (idx < 196608) {
        int j = idx >> 8, k = idx & 255;
        const float* W = (j < 256) ? Wq : (j < 512) ? Wk : Wv;
        WT[idx] = f2bf(W[k * 256 + (j & 255)]);
    } else {
        int t = idx - 196608;
        int j = t >> 8, k = t & 255;
        WOT[t] = f2bf(Wo[k * 256 + j]);
    }
}

// ---------------------------------------------------------------------------
// QKV projection: C[65536,768] = relu(X[65536,256] @ W + b), bf16 out.
// ---------------------------------------------------------------------------
__global__ __launch_bounds__(256, 2) void qkv_gemm(
    const float* __restrict__ X, const u16* __restrict__ WT,
    const float* __restrict__ bQ, const float* __restrict__ bK,
    const float* __restrict__ bV,
    u16* __restrict__ outQ, u16* __restrict__ outK, u16* __restrict__ outVT)
{
    __shared__ __align__(16) u16 As[128 * 256];  // 64KB, XOR-swizzled rows
    __shared__ __align__(16) u16 Bs[128 * 64];   // 16KB, XOR-swizzled rows
    const int tid = threadIdx.x;
    const int m0 = blockIdx.x * 128;

    #pragma unroll
    for (int i = 0; i < 32; ++i) {
        int flat = (i * 256 + tid) * 4;
        int r = flat >> 8, c = flat & 255;
        const f32x4 f = *reinterpret_cast<const f32x4*>(X + (size_t)(m0 + r) * 256 + c);
        ushort4v h;
        h.x = f2bf(f.x); h.y = f2bf(f.y); h.z = f2bf(f.z); h.w = f2bf(f.w);
        int byte = (r * 512 + c * 2) ^ ((r & 7) << 4);
        *reinterpret_cast<ushort4v*>(reinterpret_cast<char*>(As) + byte) = h;
    }

    const int lane = tid & 63, wid = tid >> 6;
    const int wr = wid >> 1, wc = wid & 1;
    const int lr = lane & 15, lg = lane >> 4;

    for (int cb = 0; cb < 6; ++cb) {
        const int jbase = cb * 128;
        f32x4 acc[4][4];
        #pragma unroll
        for (int a = 0; a < 4; ++a)
            #pragma unroll
            for (int b = 0; b < 4; ++b) acc[a][b] = (f32x4){0.f, 0.f, 0.f, 0.f};

        for (int kk = 0; kk < 256; kk += 64) {
            __syncthreads();
            #pragma unroll
            for (int i = 0; i < 4; ++i) {
                int e = (i * 256 + tid) * 8;
                int r = e >> 6, c = e & 63;
                ushort8 d = *reinterpret_cast<const ushort8*>(WT + (size_t)(jbase + r) * 256 + kk + c);
                int byte = (r * 128 + c * 2) ^ ((r & 7) << 4);
                *reinterpret_cast<ushort8*>(reinterpret_cast<char*>(Bs) + byte) = d;
            }
            __syncthreads();
            #pragma unroll
            for (int ks = 0; ks < 2; ++ks) {
                bf16x8 af[4], bfr[4];
                #pragma unroll
                for (int mt = 0; mt < 4; ++mt) {
                    int r = wr * 64 + mt * 16 + lr;
                    int byte = (r * 512 + (kk + ks * 32 + lg * 8) * 2) ^ ((r & 7) << 4);
                    af[mt] = *reinterpret_cast<const bf16x8*>(reinterpret_cast<const char*>(As) + byte);
                }
                #pragma unroll
                for (int nt = 0; nt < 4; ++nt) {
                    int r = wc * 64 + nt * 16 + lr;
                    int byte = (r * 128 + (ks * 32 + lg * 8) * 2) ^ ((r & 7) << 4);
                    bfr[nt] = *reinterpret_cast<const bf16x8*>(reinterpret_cast<const char*>(Bs) + byte);
                }
                #pragma unroll
                for (int mt = 0; mt < 4; ++mt)
                    #pragma unroll
                    for (int nt = 0; nt < 4; ++nt)
                        acc[mt][nt] = mfma16(af[mt], bfr[nt], acc[mt][nt]);
            }
        }
        const float* bias = (cb < 2) ? bQ : (cb < 4) ? bK : bV;
        float bcol[4];
        #pragma unroll
        for (int nt = 0; nt < 4; ++nt)
            bcol[nt] = bias[(jbase + wc * 64 + nt * 16 + lr) & 255];
        #pragma unroll
        for (int mt = 0; mt < 4; ++mt) {
            #pragma unroll
            for (int nt = 0; nt < 4; ++nt) {
                #pragma unroll
                for (int j = 0; j < 4; ++j) {
                    float v = fmaxf(acc[mt][nt][j] + bcol[nt], 0.f);
                    u16 h = f2bf(v);
                    int row = m0 + wr * 64 + mt * 16 + lg * 4 + j;
                    int col = jbase + wc * 64 + nt * 16 + lr;
                    if (cb < 2) {
                        outQ[(size_t)row * 256 + col] = h;
                    } else if (cb < 4) {
                        outK[(size_t)row * 256 + (col - 256)] = h;
                    } else {
                        int bb = row >> 9, n = row & 511;
                        outVT[(size_t)bb * 131072 + (size_t)(col - 512) * 512 + n] = h;
                    }
                }
            }
        }
    }
}

// ---------------------------------------------------------------------------
// Flash attention r11 = r8 staging + SWAPPED QK^T (S^T in regs):
//   mfma(K, Q) -> lane owns q = n0+lr (column), keys = ct*16 + lg*4 + j.
//   softmax: scalar m/l per lane; reduce = 7 fmax + shfl_xor(16,32).
//   P^T -> p_lds [q][key] rows 80B (conflict-free): 2 b64 writes + 1 b128 read.
//   PV: O^T = mfma(V^T, P^T); V LDS chunk-swizzled (^row&3, 2-way = free).
//   Output O^T stored as packed ushort4 per ht.
// ---------------------------------------------------------------------------
__global__ __launch_bounds__(512) void attn_kernel(
    const u16* __restrict__ Q, const u16* __restrict__ K,
    const u16* __restrict__ VT, const float* __restrict__ Mask,
    u16* __restrict__ Out)
{
    __shared__ __align__(16) u16 k_lds[2][32 * 256];  // 2 x 16KB, XOR-swizzled
    __shared__ __align__(16) u16 v_lds[2][256 * 32];  // 2 x 16KB, chunk-swizzled
    __shared__ __align__(16) char p_lds[8 * 1280];    // per-wave [16 q][80B]
    const int tid = threadIdx.x;          // 0..511
    const int b  = blockIdx.x & 127;      // batch; 4 blocks/batch on one XCD
    const int rb = blockIdx.x >> 7;       // 0..3
    const int lane = tid & 63, wid = tid >> 6;
    const int lr = lane & 15, lg = lane >> 4;
    const int n0 = rb * 128 + wid * 16;
    const u16* qbat = Q  + (size_t)b * 131072;
    const u16* kbat = K  + (size_t)b * 131072;
    const u16* vbat = VT + (size_t)b * 131072;
    // mask base for this lane's q-row (q = n0 + lr)
    const float* mbase = Mask + ((size_t)b * 512 + n0 + lr) * 512;
    char* pw = p_lds + wid * 1280;

    auto stage = [&](int buf, int kt) {
        #pragma unroll
        for (int i = 0; i < 2; ++i) {
            int p = (i * 512 + tid) * 16;
            // K: rows 512B; src col ^= (row&7)<<4
            int krow = p >> 9, kcol2 = p & 511;
            int scol2 = kcol2 ^ ((krow & 7) << 4);
            const char* gk = reinterpret_cast<const char*>(kbat + (size_t)(kt * 32 + krow) * 256) + scol2;
            char* lk = reinterpret_cast<char*>(k_lds[buf]) + i * 8192 + wid * 1024;
            gload_lds16(gk, lk);
            // V: rows 64B (4 chunks of 16B); src chunk ^= row&3 (2-way free)
            int vrow = p >> 6;
            int chunk = (p >> 4) & 3;
            int schunk = chunk ^ (vrow & 3);
            const char* gv = reinterpret_cast<const char*>(vbat + (size_t)vrow * 512 + kt * 32) + schunk * 16;
            char* lv = reinterpret_cast<char*>(v_lds[buf]) + i * 8192 + wid * 1024;
            gload_lds16(gv, lv);
        }
    };

    // persistent Q fragments: row n0+lr, all 256 K-dim (8 chunks of 32)
    bf16x8 qf[8];
    #pragma unroll
    for (int ks = 0; ks < 8; ++ks)
        qf[ks] = *reinterpret_cast<const bf16x8*>(
            qbat + (size_t)(n0 + lr) * 256 + ks * 32 + lg * 8);

    stage(0, 0);
    // mask prefetch kt=0: mf[ct] = mask[q=n0+lr][keys ct*16 + lg*4 + 0..3]
    f32x4 mf[2];
    #pragma unroll
    for (int ct = 0; ct < 2; ++ct)
        mf[ct] = __builtin_nontemporal_load(
            reinterpret_cast<const f32x4*>(mbase + ct * 16 + lg * 4));

    f32x4 acc[16];   // acc[ht][j] = O^T[h = ht*16 + lg*4 + j][q = n0+lr]
    #pragma unroll
    for (int i = 0; i < 16; ++i) acc[i] = (f32x4){0.f, 0.f, 0.f, 0.f};
    float mreg = -__builtin_inff(), lreg = 0.f;

    __syncthreads();

    for (int kt = 0; kt < 16; ++kt) {
        const int cur = kt & 1;
        if (kt < 15) stage(cur ^ 1, kt + 1);

        // pack current mask bits (ct*4+j), then prefetch next tile
        u32 mb = 0;
        #pragma unroll
        for (int ct = 0; ct < 2; ++ct)
            #pragma unroll
            for (int j = 0; j < 4; ++j)
                mb |= (mf[ct][j] > 0.5f ? 1u : 0u) << (ct * 4 + j);
        if (kt < 15) {
            #pragma unroll
            for (int ct = 0; ct < 2; ++ct)
                mf[ct] = __builtin_nontemporal_load(reinterpret_cast<const f32x4*>(
                    mbase + (kt + 1) * 32 + ct * 16 + lg * 4));
        }

        // ---- S^T = K Q^T : keys (rows) x 16 q (cols) per wave ----
        f32x4 s[2];
        s[0] = (f32x4){0.f, 0.f, 0.f, 0.f};
        s[1] = (f32x4){0.f, 0.f, 0.f, 0.f};
        const char* kbase = reinterpret_cast<const char*>(k_lds[cur]);
        __builtin_amdgcn_s_setprio(1);
        #pragma unroll
        for (int ks = 0; ks < 8; ++ks) {
            #pragma unroll
            for (int ct = 0; ct < 2; ++ct) {
                int krow = ct * 16 + lr;
                int byte = (krow * 512 + (ks * 32 + lg * 8) * 2) ^ ((krow & 7) << 4);
                bf16x8 kf = *reinterpret_cast<const bf16x8*>(kbase + byte);
                s[ct] = mfma16(kf, qf[ks], s[ct]);   // SWAPPED: D = S^T
            }
        }
        __builtin_amdgcn_s_setprio(0);

        // ---- mask select (keys ct*16+lg*4+j for q=lr) ----
        float p[2][4];
        #pragma unroll
        for (int ct = 0; ct < 2; ++ct)
            #pragma unroll
            for (int j = 0; j < 4; ++j)
                p[ct][j] = ((mb >> (ct * 4 + j)) & 1u) ? s[ct][j] : -9.0e15f;

        // ---- online softmax, scalar state (q is lane-local) ----
        float r0 = p[0][0];
        r0 = fmaxf(r0, p[0][1]); r0 = fmaxf(r0, p[0][2]); r0 = fmaxf(r0, p[0][3]);
        r0 = fmaxf(r0, p[1][0]); r0 = fmaxf(r0, p[1][1]);
        r0 = fmaxf(r0, p[1][2]); r0 = fmaxf(r0, p[1][3]);
        r0 = fmaxf(r0, __shfl_xor(r0, 16));
        r0 = fmaxf(r0, __shfl_xor(r0, 32));
        bool need = (r0 > mreg);
        if (__any(need)) {
            float mnew = fmaxf(mreg, r0);
            float sc = __expf(mreg - mnew);
            mreg = mnew;
            lreg *= sc;
            #pragma unroll
            for (int ht = 0; ht < 16; ++ht) {
                acc[ht][0] *= sc; acc[ht][1] *= sc;
                acc[ht][2] *= sc; acc[ht][3] *= sc;
            }
        }
        float ps = 0.f;
        #pragma unroll
        for (int ct = 0; ct < 2; ++ct)
            #pragma unroll
            for (int j = 0; j < 4; ++j) {
                float e = __expf(p[ct][j] - mreg);
                p[ct][j] = e;
                ps += e;
            }
        lreg += ps;

        // ---- P^T -> p_lds [q=lr][key], 80B rows: 2 x b64 writes ----
        #pragma unroll
        for (int ct = 0; ct < 2; ++ct) {
            ushort4v w;
            w.x = f2bf(p[ct][0]); w.y = f2bf(p[ct][1]);
            w.z = f2bf(p[ct][2]); w.w = f2bf(p[ct][3]);
            *reinterpret_cast<ushort4v*>(pw + lr * 80 + ct * 32 + lg * 8) = w;
        }

        // ---- PV: O^T += V^T[h][key] * P^T[key][q], one mfma per ht ----
        bf16x8 pf = *reinterpret_cast<const bf16x8*>(pw + lr * 80 + lg * 16);
        const char* vbase = reinterpret_cast<const char*>(v_lds[cur]);
        __builtin_amdgcn_s_setprio(1);
        #pragma unroll
        for (int ht = 0; ht < 16; ++ht) {
            int hrow = ht * 16 + lr;
            int byte = (hrow * 64 + lg * 16) ^ ((hrow & 3) << 4);
            bf16x8 vf = *reinterpret_cast<const bf16x8*>(vbase + byte);
            acc[ht] = mfma16(vf, pf, acc[ht]);
        }
        __builtin_amdgcn_s_setprio(0);

        __syncthreads();  // next tile staged (vmcnt drained); LDS reads done
    }

    // finalize: l reduced over lg groups; store O^T rows as packed ushort4
    float lt = lreg;
    lt += __shfl_xor(lt, 16);
    lt += __shfl_xor(lt, 32);
    float inv = 1.0f / lt;
    u16* orow = Out + ((size_t)b * 512 + n0 + lr) * 256;
    #pragma unroll
    for (int ht = 0; ht < 16; ++ht) {
        ushort4v w;
        w.x = f2bf(acc[ht][0] * inv); w.y = f2bf(acc[ht][1] * inv);
        w.z = f2bf(acc[ht][2] * inv); w.w = f2bf(acc[ht][3] * inv);
        *reinterpret_cast<ushort4v*>(orow + ht * 16 + lg * 4) = w;
    }
}

// ---------------------------------------------------------------------------
// Output projection: Out[65536,256] = relu(A[65536,256](bf16) @ Wo + bo), f32.
// ---------------------------------------------------------------------------
__global__ __launch_bounds__(256, 2) void out_gemm(
    const u16* __restrict__ A, const u16* __restrict__ WOT,
    const float* __restrict__ bO, float* __restrict__ Out)
{
    __shared__ __align__(16) u16 As[128 * 256];
    __shared__ __align__(16) u16 Bs[128 * 64];
    const int tid = threadIdx.x;
    const int m0 = blockIdx.x * 128;

    #pragma unroll
    for (int i = 0; i < 16; ++i) {
        int e = (i * 256 + tid) * 8;
        int r = e >> 8, c = e & 255;
        ushort8 d = *reinterpret_cast<const ushort8*>(A + (size_t)(m0 + r) * 256 + c);
        int byte = (r * 512 + c * 2) ^ ((r & 7) << 4);
        *reinterpret_cast<ushort8*>(reinterpret_cast<char*>(As) + byte) = d;
    }

    const int lane = tid & 63, wid = tid >> 6;
    const int wr = wid >> 1, wc = wid & 1;
    const int lr = lane & 15, lg = lane >> 4;

    for (int cb = 0; cb < 2; ++cb) {
        const int jbase = cb * 128;
        f32x4 acc[4][4];
        #pragma unroll
        for (int a = 0; a < 4; ++a)
            #pragma unroll
            for (int b = 0; b < 4; ++b) acc[a][b] = (f32x4){0.f, 0.f, 0.f, 0.f};

        for (int kk = 0; kk < 256; kk += 64) {
            __syncthreads();
            #pragma unroll
            for (int i = 0; i < 4; ++i) {
                int e = (i * 256 + tid) * 8;
                int r = e >> 6, c = e & 63;
                ushort8 d = *reinterpret_cast<const ushort8*>(WOT + (size_t)(jbase + r) * 256 + kk + c);
                int byte = (r * 128 + c * 2) ^ ((r & 7) << 4);
                *reinterpret_cast<ushort8*>(reinterpret_cast<char*>(Bs) + byte) = d;
            }
            __syncthreads();
            #pragma unroll
            for (int ks = 0; ks < 2; ++ks) {
                bf16x8 af[4], bfr[4];
                #pragma unroll
                for (int mt = 0; mt < 4; ++mt) {
                    int r = wr * 64 + mt * 16 + lr;
                    int byte = (r * 512 + (kk + ks * 32 + lg * 8) * 2) ^ ((r & 7) << 4);
                    af[mt] = *reinterpret_cast<const bf16x8*>(reinterpret_cast<const char*>(As) + byte);
                }
                #pragma unroll
                for (int nt = 0; nt < 4; ++nt) {
                    int r = wc * 64 + nt * 16 + lr;
                    int byte = (r * 128 + (ks * 32 + lg * 8) * 2) ^ ((r & 7) << 4);
                    bfr[nt] = *reinterpret_cast<const bf16x8*>(reinterpret_cast<const char*>(Bs) + byte);
                }
                #pragma unroll
                for (int mt = 0; mt < 4; ++mt)
                    #pragma unroll
                    for (int nt = 0; nt < 4; ++nt)
                        acc[mt][nt] = mfma16(af[mt], bfr[nt], acc[mt][nt]);
            }
        }
        float bcol[4];
        #pragma unroll
        for (int nt = 0; nt < 4; ++nt)
            bcol[nt] = bO[jbase + wc * 64 + nt * 16 + lr];
        #pragma unroll
        for (int mt = 0; mt < 4; ++mt) {
            #pragma unroll
            for (int nt = 0; nt < 4; ++nt) {
                #pragma unroll
                for (int j = 0; j < 4; ++j) {
                    float v = fmaxf(acc[mt][nt][j] + bcol[nt], 0.f);
                    int row = m0 + wr * 64 + mt * 16 + lg * 4 + j;
                    int col = jbase + wc * 64 + nt * 16 + lr;
                    Out[(size_t)row * 256 + col] = v;
                }
            }
        }
    }
}

// ---------------------------------------------------------------------------
extern "C" void kernel_launch(void* const* d_in, const int* in_sizes, int n_in,
                              void* d_out, int out_size, void* d_ws, size_t ws_size,
                              hipStream_t stream) {
    const float* x    = (const float*)d_in[0];
    const float* mask = (const float*)d_in[1];
    const float* Wv   = (const float*)d_in[2];
    const float* bv   = (const float*)d_in[3];
    const float* Wk   = (const float*)d_in[4];
    const float* bk   = (const float*)d_in[5];
    const float* Wq   = (const float*)d_in[6];
    const float* bq   = (const float*)d_in[7];
    const float* Wo   = (const float*)d_in[8];
    const float* bo   = (const float*)d_in[9];
    float* out = (float*)d_out;

    char* ws = (char*)d_ws;
    u16* WT  = (u16*)(ws);                          // 768*256 bf16 = 384KB
    u16* WOT = (u16*)(ws + 393216);                 // 256*256 bf16 = 128KB
    u16* Qb  = (u16*)(ws + 524288);                 // 33.55MB (also attn out)
    u16* Kb  = (u16*)(ws + 524288 + 33554432);      // 33.55MB
    u16* VTb = (u16*)(ws + 524288 + 2 * 33554432);  // 33.55MB, [b][h][n]

    prep_w<<<1024, 256, 0, stream>>>(Wq, Wk, Wv, Wo, WT, WOT);
    qkv_gemm<<<512, 256, 0, stream>>>(x, WT, bq, bk, bv, Qb, Kb, VTb);
    attn_kernel<<<512, 512, 0, stream>>>(Qb, Kb, VTb, mask, Qb);
    out_gemm<<<512, 256, 0, stream>>>(Qb, WOT, bo, out);
}